// Round 11
// baseline (104.003 us; speedup 1.0000x reference)
//
#include <hip/hip_runtime.h>
#include <cstdint>
#include <cstddef>

typedef __attribute__((ext_vector_type(8))) short bf16x8;
typedef __attribute__((ext_vector_type(4))) short short4v;
typedef __attribute__((ext_vector_type(4))) float f32x4;
typedef __attribute__((ext_vector_type(2))) unsigned int u32x2;
typedef __attribute__((ext_vector_type(4))) unsigned int u32x4;

extern "C" __device__ float __ocml_native_exp2_f32(float);
#define EXP2 __ocml_native_exp2_f32

__device__ __forceinline__ unsigned cvt_pk_bf16(float a, float b) {
  unsigned r;
  asm("v_cvt_pk_bf16_f32 %0, %1, %2" : "=v"(r) : "v"(a), "v"(b));
  return r;
}

__device__ __forceinline__ short f2bf(float f) {
  unsigned u = __float_as_uint(f);
  u += 0x7FFFu + ((u >> 16) & 1u);
  return (short)(u >> 16);
}

// timescale[r] = 10000^(r/16) = 10^(r/4); these are 1/timescale
__constant__ float INV_TS[8] = {
  1.0f, 0.5623413251903491f, 0.31622776601683794f, 0.17782794100389228f,
  0.1f, 0.05623413251903491f, 0.031622776601683794f, 0.017782794100389228f
};

// ---------------------------------------------------------------------------
// QKV GEMM with FUSED rope + scale + bf16 pack + V transpose in the epilogue.
// Q pre-scaled by hd^-0.5 * LOG2E so attention computes exp2(S + lb) directly.
// (proven rounds 6/9/10, verbatim)
// ---------------------------------------------------------------------------
__global__ __launch_bounds__(256) void gemm_qkv_rope(
    const float* __restrict__ X,
    const float* __restrict__ W0, const float* __restrict__ W1, const float* __restrict__ W2,
    const float* __restrict__ b0, const float* __restrict__ b1, const float* __restrict__ b2,
    short* __restrict__ Qo, short* __restrict__ Ko, short* __restrict__ Vt)
{
  __shared__ short sA[128 * 40];
  __shared__ short sB[64 * 40];
  const int t = threadIdx.x;
  const int w = t >> 6, l = t & 63;
  const int l15 = l & 15, lg = l >> 4;
  const int rbase = blockIdx.x * 128;
  const int cgbase = blockIdx.y * 64;
  const int mat = cgbase >> 8;
  const float* W = (mat == 0) ? W0 : ((mat == 1) ? W1 : W2);
  const float* bias = (mat == 0) ? b0 : ((mat == 1) ? b1 : b2);
  const int wbase = cgbase & 255;

  const int ar = t >> 1, akc = (t & 1) * 16;
  const int br = t >> 2, bkc = (t & 3) * 8;

  const float* Bg = W + (size_t)(wbase + br) * 256 + bkc;
  const float* Agf = X + (size_t)(rbase + ar) * 256 + akc;

  const int wr = w >> 1, wc = w & 1;

  f32x4 acc[4][2];
#pragma unroll
  for (int i = 0; i < 4; ++i) {
    acc[i][0] = {0.f, 0.f, 0.f, 0.f};
    acc[i][1] = {0.f, 0.f, 0.f, 0.f};
  }

  for (int k0 = 0; k0 < 256; k0 += 32) {
    f32x4 a0 = *(const f32x4*)(Agf + k0);
    f32x4 a1 = *(const f32x4*)(Agf + k0 + 4);
    f32x4 a2 = *(const f32x4*)(Agf + k0 + 8);
    f32x4 a3 = *(const f32x4*)(Agf + k0 + 12);
    u32x4 pa0, pa1;
    pa0.x = cvt_pk_bf16(a0[0], a0[1]); pa0.y = cvt_pk_bf16(a0[2], a0[3]);
    pa0.z = cvt_pk_bf16(a1[0], a1[1]); pa0.w = cvt_pk_bf16(a1[2], a1[3]);
    pa1.x = cvt_pk_bf16(a2[0], a2[1]); pa1.y = cvt_pk_bf16(a2[2], a2[3]);
    pa1.z = cvt_pk_bf16(a3[0], a3[1]); pa1.w = cvt_pk_bf16(a3[2], a3[3]);
    f32x4 bv0 = *(const f32x4*)(Bg + k0);
    f32x4 bv1 = *(const f32x4*)(Bg + k0 + 4);
    u32x4 pb;
    pb.x = cvt_pk_bf16(bv0[0], bv0[1]); pb.y = cvt_pk_bf16(bv0[2], bv0[3]);
    pb.z = cvt_pk_bf16(bv1[0], bv1[1]); pb.w = cvt_pk_bf16(bv1[2], bv1[3]);

    __syncthreads();
    *(u32x4*)(sA + ar * 40 + akc)     = pa0;
    *(u32x4*)(sA + ar * 40 + akc + 8) = pa1;
    *(u32x4*)(sB + br * 40 + bkc)     = pb;
    __syncthreads();

    bf16x8 af[4], bfr[2];
#pragma unroll
    for (int i = 0; i < 4; ++i)
      af[i] = *(const bf16x8*)(sA + (wr * 64 + i * 16 + l15) * 40 + lg * 8);
#pragma unroll
    for (int j = 0; j < 2; ++j)
      bfr[j] = *(const bf16x8*)(sB + (wc * 32 + j * 16 + l15) * 40 + lg * 8);
#pragma unroll
    for (int i = 0; i < 4; ++i)
#pragma unroll
      for (int j = 0; j < 2; ++j)
        acc[i][j] = __builtin_amdgcn_mfma_f32_16x16x32_bf16(af[i], bfr[j], acc[i][j], 0, 0, 0);
  }

  const int cm = wbase + wc * 32;
  const int hh = cm >> 5;
  const float bv0 = bias[cm + l15];
  const float bv1 = bias[cm + 16 + l15];
  // hd^-0.5 * log2(e): attention computes exp2(S + lb) with no multiply
  const float SCL_Q = 0.17677669529663687f * 1.4426950408889634f;

#pragma unroll
  for (int i = 0; i < 4; ++i) {
    const int m0 = rbase + wr * 64 + i * 16 + lg * 4;
    const int b = m0 >> 12, n0 = m0 & 4095;
    if (mat < 2) {
      short* dst = (mat == 0 ? Qo : Ko) + (size_t)(b * 8 + hh) * 131072 + (size_t)n0 * 32 + l15;
#pragma unroll
      for (int jj = 0; jj < 4; ++jj) {
        float v0 = acc[i][0][jj] + bv0;
        float v1 = acc[i][1][jj] + bv1;
        if (mat == 0) { v0 *= SCL_Q; v1 *= SCL_Q; }
        if (l15 < 8) {
          float ang = (float)(n0 + jj) * INV_TS[l15];
          float s = sinf(ang), c = cosf(ang);
          float r0 = v0 * c - v1 * s;
          float r1 = v1 * c + v0 * s;
          v0 = r0; v1 = r1;
        }
        dst[jj * 32]      = f2bf(v0);
        dst[jj * 32 + 16] = f2bf(v1);
      }
    } else {
      short* dstv = Vt + (size_t)(b * 8 + hh) * 131072 + n0;
#pragma unroll
      for (int j = 0; j < 2; ++j) {
        const float bv = j ? bv1 : bv0;
        short4v pk;
#pragma unroll
        for (int jj = 0; jj < 4; ++jj) pk[jj] = f2bf(acc[i][j][jj] + bv);
        *(short4v*)(dstv + (size_t)(j * 16 + l15) * 4096) = pk;
      }
    }
  }
}

// ---------------------------------------------------------------------------
// Flash attention v9: round-10 structure with HALVED q-tile — 64 q-rows/block
// (16 per wave, single fragment) -> grid 2048 blocks = 8 blocks/CU demanded,
// ~5 resident (LDS cap). Double-buffered K/V, 1 barrier/kt, K=32 PV through
// per-wave 16-row LDS-P. Q pre-scaled by hd^-0.5*log2e: p = exp2(S + lb).
// Grid: (4096/64, 16, 2).
// ---------------------------------------------------------------------------
__global__ __launch_bounds__(256, 4) void attn_fwd(
    const short* __restrict__ Qg, const short* __restrict__ Kg, const short* __restrict__ Vg,
    const float* __restrict__ ab, const int* __restrict__ slp,
    float* __restrict__ Op, float* __restrict__ denp)
{
  __shared__ short sK[2][64 * 40];   // [key][dim], stride 40
  __shared__ short sV[2][32 * 72];   // [dim][key], stride 72
  __shared__ short sP[4][16 * 72];   // per-wave P [16 q][64 k]
  const int t = threadIdx.x, w = t >> 6, l = t & 63;
  const int l15 = l & 15, lg = l >> 4;
  const int bh = blockIdx.y, h = bh & 7;
  const int z = blockIdx.z;
  const int qb = blockIdx.x * 64 + w * 16;
  const int sl = *slp;

  const short* Qb = Qg + (size_t)bh * (4096 * 32);
  const short* Kb = Kg + (size_t)bh * (4096 * 32);
  const short* Vb = Vg + (size_t)bh * (32 * 4096);

  bf16x8 qf = *(const bf16x8*)(Qb + (size_t)(qb + l15) * 32 + lg * 8);

  const float LOG2E = 1.4426950408889634f;
  const float lbs = ab[h * 2] * LOG2E, lbd = ab[h * 2 + 1] * LOG2E;
  const int qv  = (qb + l15) / sl;
  const int qlo = qv * sl;

  short* P = &sP[w][0];
  short* pw = P + l15 * 72 + lg * 4;         // write: q-row l15, keys lg*4 (+t4*16)
  const short* pr = P + l15 * 72 + lg * 8;   // read: A-frag, k = lg*8 (+kk*32)

  const f32x4 fz = {0.f, 0.f, 0.f, 0.f};
  f32x4 Oacc[2];
  Oacc[0] = fz; Oacc[1] = fz;
  float den = 0.f;

  const int kt0 = z * 32, kt1 = kt0 + 32;
  const int kstart = kt0 * 64;

  const int kr = t >> 2, kc0 = (t & 3) * 8;
  const int vd = t >> 3, vk0 = (t & 7) * 8;
  const short* kg = Kb + (size_t)(kstart + kr) * 32 + kc0;
  const short* vg = Vb + (size_t)vd * 4096 + kstart + vk0;

  bf16x8 krg = *(const bf16x8*)kg;
  bf16x8 vrg = *(const bf16x8*)vg;
  *(bf16x8*)(&sK[0][0] + kr * 40 + kc0) = krg;
  *(bf16x8*)(&sV[0][0] + vd * 72 + vk0) = vrg;
  kg += 64 * 32; vg += 64;
  krg = *(const bf16x8*)kg;
  vrg = *(const bf16x8*)vg;
  __syncthreads();

  int kv = kstart / sl;
  int rem = (kv + 1) * sl - kstart;
  int cur = 0;

#pragma unroll 2
  for (int kt = kt0; kt < kt1; ++kt) {
    // park tile kt+1 (loaded last iter) into buf[cur^1]
    *(bf16x8*)(&sK[cur ^ 1][0] + kr * 40 + kc0) = krg;
    *(bf16x8*)(&sV[cur ^ 1][0] + vd * 72 + vk0) = vrg;
    // issue global loads for tile kt+2
    const int adv = (kt + 2 < kt1) ? 1 : 0;
    kg += adv * (64 * 32); vg += adv * 64;
    krg = *(const bf16x8*)kg;
    vrg = *(const bf16x8*)vg;

    const short* sKc = &sK[cur][0];
    const short* sVc = &sV[cur][0];

    // S^T = K . Q^T : lane holds q-row l15, keys t4*16 + lg*4 + j
    f32x4 S[4];
#pragma unroll
    for (int t4 = 0; t4 < 4; ++t4) {
      bf16x8 kf = *(const bf16x8*)(sKc + (t4 * 16 + l15) * 40 + lg * 8);
      S[t4] = __builtin_amdgcn_mfma_f32_16x16x32_bf16(kf, qf, fz, 0, 0, 0);
    }

    const int kb0 = kt * 64;
    const float lb = (qv == kv) ? lbs : lbd;
    if (rem >= 64) {
#pragma unroll
      for (int t4 = 0; t4 < 4; ++t4) {
        float p0 = EXP2(S[t4][0] + lb);
        float p1 = EXP2(S[t4][1] + lb);
        float p2 = EXP2(S[t4][2] + lb);
        float p3 = EXP2(S[t4][3] + lb);
        den += (p0 + p1) + (p2 + p3);
        u32x2 u; u.x = cvt_pk_bf16(p0, p1); u.y = cvt_pk_bf16(p2, p3);
        *(u32x2*)(pw + t4 * 16) = u;
      }
    } else {
#pragma unroll
      for (int t4 = 0; t4 < 4; ++t4) {
        const int gk = kb0 + t4 * 16 + lg * 4;
        float p[4];
#pragma unroll
        for (int j = 0; j < 4; ++j) {
          float lbj = ((unsigned)(gk + j - qlo) < (unsigned)sl) ? lbs : lbd;
          p[j] = EXP2(S[t4][j] + lbj);
          den += p[j];
        }
        u32x2 u; u.x = cvt_pk_bf16(p[0], p[1]); u.y = cvt_pk_bf16(p[2], p[3]);
        *(u32x2*)(pw + t4 * 16) = u;
      }
    }
    rem -= 64;
    while (rem <= 0) { kv += 1; rem += sl; }

    // O += P . V  (same-wave LDS dependency; compiler inserts lgkmcnt)
#pragma unroll
    for (int kk = 0; kk < 2; ++kk) {
      bf16x8 pf = *(const bf16x8*)(pr + kk * 32);
      bf16x8 vf0 = *(const bf16x8*)(sVc + l15 * 72 + kk * 32 + lg * 8);
      bf16x8 vf1 = *(const bf16x8*)(sVc + (16 + l15) * 72 + kk * 32 + lg * 8);
      Oacc[0] = __builtin_amdgcn_mfma_f32_16x16x32_bf16(pf, vf0, Oacc[0], 0, 0, 0);
      Oacc[1] = __builtin_amdgcn_mfma_f32_16x16x32_bf16(pf, vf1, Oacc[1], 0, 0, 0);
    }

    __syncthreads();
    cur ^= 1;
  }

  // reduce den across lg groups (lanes with same l15)
  den += __shfl_xor(den, 16, 64);
  den += __shfl_xor(den, 32, 64);

  const size_t zb = ((size_t)z * 16 + bh) * 4096;
  if (lg == 0)
    denp[zb + qb + l15] = den;
#pragma unroll
  for (int nt = 0; nt < 2; ++nt)
#pragma unroll
    for (int j = 0; j < 4; ++j) {
      const int n = qb + lg * 4 + j;
      Op[(zb + n) * 32 + nt * 16 + l15] = Oacc[nt][j];
    }
}

// ---------------------------------------------------------------------------
// Combine K-split partials: attno[b][n][h*32+d] = (O0+O1)/(d0+d1) as bf16.
// ---------------------------------------------------------------------------
__global__ __launch_bounds__(256) void combine(
    const float* __restrict__ Op, const float* __restrict__ denp,
    short* __restrict__ attno)
{
  const int id = blockIdx.x * 256 + threadIdx.x;   // 16*4096*8
  const int d4 = (id & 7) * 4;
  const int n  = (id >> 3) & 4095;
  const int bh = id >> 15;
  const size_t base = ((size_t)bh * 4096 + n) * 32 + d4;
  const size_t zoff = (size_t)16 * 4096 * 32;
  f32x4 o0 = *(const f32x4*)(Op + base);
  f32x4 o1 = *(const f32x4*)(Op + zoff + base);
  const float rd = 1.0f / (denp[bh * 4096 + n] + denp[16 * 4096 + bh * 4096 + n]);
  const int b = bh >> 3, hh = bh & 7;
  u32x2 u;
  u.x = cvt_pk_bf16((o0[0] + o1[0]) * rd, (o0[1] + o1[1]) * rd);
  u.y = cvt_pk_bf16((o0[2] + o1[2]) * rd, (o0[3] + o1[3]) * rd);
  *(u32x2*)(attno + ((size_t)(b * 4096 + n) * 256 + hh * 32 + d4)) = u;
}

// ---------------------------------------------------------------------------
// o-proj GEMM (proven, verbatim; A_BF16=1, OUT_BF16=0)
// ---------------------------------------------------------------------------
template<int A_BF16, int OUT_BF16>
__global__ __launch_bounds__(256) void gemm_mfma(
    const void* __restrict__ Ain,
    const float* __restrict__ W0, const float* __restrict__ W1, const float* __restrict__ W2,
    const float* __restrict__ b0, const float* __restrict__ b1, const float* __restrict__ b2,
    void* __restrict__ Cout, int Ntot)
{
  __shared__ short sA[128 * 40];
  __shared__ short sB[64 * 40];
  const int t = threadIdx.x;
  const int w = t >> 6, l = t & 63;
  const int l15 = l & 15, lg = l >> 4;
  const int rbase = blockIdx.x * 128;
  const int cgbase = blockIdx.y * 64;
  const int mat = cgbase >> 8;
  const float* W = (mat == 0) ? W0 : ((mat == 1) ? W1 : W2);
  const float* bias = (mat == 0) ? b0 : ((mat == 1) ? b1 : b2);
  const int wbase = cgbase & 255;

  const int ar = t >> 1, akc = (t & 1) * 16;
  const int br = t >> 2, bkc = (t & 3) * 8;

  const float* Bg = W + (size_t)(wbase + br) * 256 + bkc;
  const float* Agf = (const float*)Ain + (size_t)(rbase + ar) * 256 + akc;
  const short* Agh = (const short*)Ain + (size_t)(rbase + ar) * 256 + akc;

  const int wr = w >> 1, wc = w & 1;

  f32x4 acc[4][2];
#pragma unroll
  for (int i = 0; i < 4; ++i) {
    acc[i][0] = {0.f, 0.f, 0.f, 0.f};
    acc[i][1] = {0.f, 0.f, 0.f, 0.f};
  }

  for (int k0 = 0; k0 < 256; k0 += 32) {
    u32x4 pa0, pa1;
    if constexpr (A_BF16) {
      pa0 = *(const u32x4*)(Agh + k0);
      pa1 = *(const u32x4*)(Agh + k0 + 8);
    } else {
      f32x4 a0 = *(const f32x4*)(Agf + k0);
      f32x4 a1 = *(const f32x4*)(Agf + k0 + 4);
      f32x4 a2 = *(const f32x4*)(Agf + k0 + 8);
      f32x4 a3 = *(const f32x4*)(Agf + k0 + 12);
      pa0.x = cvt_pk_bf16(a0[0], a0[1]); pa0.y = cvt_pk_bf16(a0[2], a0[3]);
      pa0.z = cvt_pk_bf16(a1[0], a1[1]); pa0.w = cvt_pk_bf16(a1[2], a1[3]);
      pa1.x = cvt_pk_bf16(a2[0], a2[1]); pa1.y = cvt_pk_bf16(a2[2], a2[3]);
      pa1.z = cvt_pk_bf16(a3[0], a3[1]); pa1.w = cvt_pk_bf16(a3[2], a3[3]);
    }
    f32x4 bv0 = *(const f32x4*)(Bg + k0);
    f32x4 bv1 = *(const f32x4*)(Bg + k0 + 4);
    u32x4 pb;
    pb.x = cvt_pk_bf16(bv0[0], bv0[1]); pb.y = cvt_pk_bf16(bv0[2], bv0[3]);
    pb.z = cvt_pk_bf16(bv1[0], bv1[1]); pb.w = cvt_pk_bf16(bv1[2], bv1[3]);

    __syncthreads();
    *(u32x4*)(sA + ar * 40 + akc)     = pa0;
    *(u32x4*)(sA + ar * 40 + akc + 8) = pa1;
    *(u32x4*)(sB + br * 40 + bkc)     = pb;
    __syncthreads();

    bf16x8 af[4], bfr[2];
#pragma unroll
    for (int i = 0; i < 4; ++i)
      af[i] = *(const bf16x8*)(sA + (wr * 64 + i * 16 + l15) * 40 + lg * 8);
#pragma unroll
    for (int j = 0; j < 2; ++j)
      bfr[j] = *(const bf16x8*)(sB + (wc * 32 + j * 16 + l15) * 40 + lg * 8);
#pragma unroll
    for (int i = 0; i < 4; ++i)
#pragma unroll
      for (int j = 0; j < 2; ++j)
        acc[i][j] = __builtin_amdgcn_mfma_f32_16x16x32_bf16(af[i], bfr[j], acc[i][j], 0, 0, 0);
  }

#pragma unroll
  for (int i = 0; i < 4; ++i)
#pragma unroll
    for (int j = 0; j < 2; ++j) {
      const int n = cgbase + wc * 32 + j * 16 + l15;
      const float bv = bias[wbase + wc * 32 + j * 16 + l15];
#pragma unroll
      for (int jj = 0; jj < 4; ++jj) {
        const size_t m = (size_t)(rbase + wr * 64 + i * 16 + lg * 4 + jj);
        const float val = acc[i][j][jj] + bv;
        if constexpr (OUT_BF16) ((short*)Cout)[m * Ntot + n] = f2bf(val);
        else                    ((float*)Cout)[m * Ntot + n] = val;
      }
    }
}

// ---------------------------------------------------------------------------
extern "C" void kernel_launch(void* const* d_in, const int* in_sizes, int n_in,
                              void* d_out, int out_size, void* d_ws, size_t ws_size,
                              hipStream_t stream) {
  (void)in_sizes; (void)n_in; (void)out_size; (void)ws_size;
  const float* hs = (const float*)d_in[0];
  const float* qw = (const float*)d_in[1];
  const float* qb = (const float*)d_in[2];
  const float* kw = (const float*)d_in[3];
  const float* kb = (const float*)d_in[4];
  const float* vw = (const float*)d_in[5];
  const float* vb = (const float*)d_in[6];
  const float* ow = (const float*)d_in[7];
  const float* ob = (const float*)d_in[8];
  const float* ab = (const float*)d_in[9];
  const int* sl   = (const int*)d_in[11];
  float* out = (float*)d_out;

  char* ws = (char*)d_ws;
  float* Op   = (float*)(ws);                    // 2*16*4096*32*4 = 16,777,216
  short* Qbf  = (short*)(ws + 16777216);         // 4,194,304
  short* Kbf  = (short*)(ws + 20971520);         // 4,194,304
  short* Vtb  = (short*)(ws + 25165824);         // 4,194,304 (transposed)
  float* denp = (float*)(ws + 29360128);         // 524,288
  short* attno= (short*)(ws + 29884416);         // 4,194,304

  // QKV projection + fused rope/scale(incl. log2e)/pack/V-transpose
  gemm_qkv_rope<<<dim3(64, 12), 256, 0, stream>>>(hs, qw, kw, vw, qb, kb, vb, Qbf, Kbf, Vtb);
  // attention (64 q-rows/block, 2048 blocks), K-split in 2
  attn_fwd<<<dim3(64, 16, 2), 256, 0, stream>>>(Qbf, Kbf, Vtb, ab, sl, Op, denp);
  // merge partials -> bf16 attention output
  combine<<<dim3(2048), 256, 0, stream>>>(Op, denp, attno);
  // output projection
  gemm_mfma<1, 0><<<dim3(64, 4), 256, 0, stream>>>(attno, ow, ow, ow, ob, ob, ob, out, 256);
}

// Round 12
// 93.466 us; speedup vs baseline: 1.1127x; 1.1127x over previous
//
#include <hip/hip_runtime.h>
#include <cstdint>
#include <cstddef>

typedef __attribute__((ext_vector_type(8))) short bf16x8;
typedef __attribute__((ext_vector_type(4))) short short4v;
typedef __attribute__((ext_vector_type(4))) float f32x4;
typedef __attribute__((ext_vector_type(2))) unsigned int u32x2;
typedef __attribute__((ext_vector_type(4))) unsigned int u32x4;

extern "C" __device__ float __ocml_native_exp2_f32(float);
#define EXP2 __ocml_native_exp2_f32

__device__ __forceinline__ unsigned cvt_pk_bf16(float a, float b) {
  unsigned r;
  asm("v_cvt_pk_bf16_f32 %0, %1, %2" : "=v"(r) : "v"(a), "v"(b));
  return r;
}

__device__ __forceinline__ short f2bf(float f) {
  unsigned u = __float_as_uint(f);
  u += 0x7FFFu + ((u >> 16) & 1u);
  return (short)(u >> 16);
}

// timescale[r] = 10000^(r/16) = 10^(r/4); these are 1/timescale
__constant__ float INV_TS[8] = {
  1.0f, 0.5623413251903491f, 0.31622776601683794f, 0.17782794100389228f,
  0.1f, 0.05623413251903491f, 0.031622776601683794f, 0.017782794100389228f
};

// ---------------------------------------------------------------------------
// QKV GEMM with FUSED rope + scale + bf16 pack + V transpose in the epilogue.
// Q pre-scaled by hd^-0.5 * LOG2E. (proven rounds 6/9/10, verbatim)
// ---------------------------------------------------------------------------
__global__ __launch_bounds__(256) void gemm_qkv_rope(
    const float* __restrict__ X,
    const float* __restrict__ W0, const float* __restrict__ W1, const float* __restrict__ W2,
    const float* __restrict__ b0, const float* __restrict__ b1, const float* __restrict__ b2,
    short* __restrict__ Qo, short* __restrict__ Ko, short* __restrict__ Vt)
{
  __shared__ short sA[128 * 40];
  __shared__ short sB[64 * 40];
  const int t = threadIdx.x;
  const int w = t >> 6, l = t & 63;
  const int l15 = l & 15, lg = l >> 4;
  const int rbase = blockIdx.x * 128;
  const int cgbase = blockIdx.y * 64;
  const int mat = cgbase >> 8;
  const float* W = (mat == 0) ? W0 : ((mat == 1) ? W1 : W2);
  const float* bias = (mat == 0) ? b0 : ((mat == 1) ? b1 : b2);
  const int wbase = cgbase & 255;

  const int ar = t >> 1, akc = (t & 1) * 16;
  const int br = t >> 2, bkc = (t & 3) * 8;

  const float* Bg = W + (size_t)(wbase + br) * 256 + bkc;
  const float* Agf = X + (size_t)(rbase + ar) * 256 + akc;

  const int wr = w >> 1, wc = w & 1;

  f32x4 acc[4][2];
#pragma unroll
  for (int i = 0; i < 4; ++i) {
    acc[i][0] = {0.f, 0.f, 0.f, 0.f};
    acc[i][1] = {0.f, 0.f, 0.f, 0.f};
  }

  for (int k0 = 0; k0 < 256; k0 += 32) {
    f32x4 a0 = *(const f32x4*)(Agf + k0);
    f32x4 a1 = *(const f32x4*)(Agf + k0 + 4);
    f32x4 a2 = *(const f32x4*)(Agf + k0 + 8);
    f32x4 a3 = *(const f32x4*)(Agf + k0 + 12);
    u32x4 pa0, pa1;
    pa0.x = cvt_pk_bf16(a0[0], a0[1]); pa0.y = cvt_pk_bf16(a0[2], a0[3]);
    pa0.z = cvt_pk_bf16(a1[0], a1[1]); pa0.w = cvt_pk_bf16(a1[2], a1[3]);
    pa1.x = cvt_pk_bf16(a2[0], a2[1]); pa1.y = cvt_pk_bf16(a2[2], a2[3]);
    pa1.z = cvt_pk_bf16(a3[0], a3[1]); pa1.w = cvt_pk_bf16(a3[2], a3[3]);
    f32x4 bv0 = *(const f32x4*)(Bg + k0);
    f32x4 bv1 = *(const f32x4*)(Bg + k0 + 4);
    u32x4 pb;
    pb.x = cvt_pk_bf16(bv0[0], bv0[1]); pb.y = cvt_pk_bf16(bv0[2], bv0[3]);
    pb.z = cvt_pk_bf16(bv1[0], bv1[1]); pb.w = cvt_pk_bf16(bv1[2], bv1[3]);

    __syncthreads();
    *(u32x4*)(sA + ar * 40 + akc)     = pa0;
    *(u32x4*)(sA + ar * 40 + akc + 8) = pa1;
    *(u32x4*)(sB + br * 40 + bkc)     = pb;
    __syncthreads();

    bf16x8 af[4], bfr[2];
#pragma unroll
    for (int i = 0; i < 4; ++i)
      af[i] = *(const bf16x8*)(sA + (wr * 64 + i * 16 + l15) * 40 + lg * 8);
#pragma unroll
    for (int j = 0; j < 2; ++j)
      bfr[j] = *(const bf16x8*)(sB + (wc * 32 + j * 16 + l15) * 40 + lg * 8);
#pragma unroll
    for (int i = 0; i < 4; ++i)
#pragma unroll
      for (int j = 0; j < 2; ++j)
        acc[i][j] = __builtin_amdgcn_mfma_f32_16x16x32_bf16(af[i], bfr[j], acc[i][j], 0, 0, 0);
  }

  const int cm = wbase + wc * 32;
  const int hh = cm >> 5;
  const float bv0 = bias[cm + l15];
  const float bv1 = bias[cm + 16 + l15];
  const float SCL_Q = 0.17677669529663687f * 1.4426950408889634f;

#pragma unroll
  for (int i = 0; i < 4; ++i) {
    const int m0 = rbase + wr * 64 + i * 16 + lg * 4;
    const int b = m0 >> 12, n0 = m0 & 4095;
    if (mat < 2) {
      short* dst = (mat == 0 ? Qo : Ko) + (size_t)(b * 8 + hh) * 131072 + (size_t)n0 * 32 + l15;
#pragma unroll
      for (int jj = 0; jj < 4; ++jj) {
        float v0 = acc[i][0][jj] + bv0;
        float v1 = acc[i][1][jj] + bv1;
        if (mat == 0) { v0 *= SCL_Q; v1 *= SCL_Q; }
        if (l15 < 8) {
          float ang = (float)(n0 + jj) * INV_TS[l15];
          float s = sinf(ang), c = cosf(ang);
          float r0 = v0 * c - v1 * s;
          float r1 = v1 * c + v0 * s;
          v0 = r0; v1 = r1;
        }
        dst[jj * 32]      = f2bf(v0);
        dst[jj * 32 + 16] = f2bf(v1);
      }
    } else {
      short* dstv = Vt + (size_t)(b * 8 + hh) * 131072 + n0;
#pragma unroll
      for (int j = 0; j < 2; ++j) {
        const float bv = j ? bv1 : bv0;
        short4v pk;
#pragma unroll
        for (int jj = 0; jj < 4; ++jj) pk[jj] = f2bf(acc[i][j][jj] + bv);
        *(short4v*)(dstv + (size_t)(j * 16 + l15) * 4096) = pk;
      }
    }
  }
}

// ---------------------------------------------------------------------------
// Flash attention v10: R10 geometry (128 q-rows/block, double-buffered K/V,
// 1 barrier/kt) + g-granular PV pipelining: PV(g1) deferred one kt iteration
// so its MFMAs overlap exp(g0) on the trans pipe; V-frags for the deferred PV
// ride in registers across the barrier. Per-wave P slots P0/P1 (16 rows each).
// Grid: (4096/128, 16, 2). Writes UNNORMALIZED partial O + den.
// ---------------------------------------------------------------------------
__global__ __launch_bounds__(256, 4) void attn_fwd(
    const short* __restrict__ Qg, const short* __restrict__ Kg, const short* __restrict__ Vg,
    const float* __restrict__ ab, const int* __restrict__ slp,
    float* __restrict__ Op, float* __restrict__ denp)
{
  __shared__ short sK[2][64 * 40];     // [key][dim], stride 40
  __shared__ short sV[2][32 * 72];     // [dim][key], stride 72
  __shared__ short sP[4][2][16 * 72];  // per-wave P slots: [wave][g][16 q][64 k]
  const int t = threadIdx.x, w = t >> 6, l = t & 63;
  const int l15 = l & 15, lg = l >> 4;
  const int bh = blockIdx.y, h = bh & 7;
  const int z = blockIdx.z;
  const int qb = blockIdx.x * 128 + w * 32;
  const int sl = *slp;

  const short* Qb = Qg + (size_t)bh * (4096 * 32);
  const short* Kb = Kg + (size_t)bh * (4096 * 32);
  const short* Vb = Vg + (size_t)bh * (32 * 4096);

  bf16x8 qf[2];
  qf[0] = *(const bf16x8*)(Qb + (size_t)(qb + l15) * 32 + lg * 8);
  qf[1] = *(const bf16x8*)(Qb + (size_t)(qb + 16 + l15) * 32 + lg * 8);

  const float LOG2E = 1.4426950408889634f;
  const float lbs = ab[h * 2] * LOG2E, lbd = ab[h * 2 + 1] * LOG2E;
  const int qv[2]  = { (qb + l15) / sl, (qb + 16 + l15) / sl };
  const int qlo[2] = { qv[0] * sl, qv[1] * sl };

  short* P0 = &sP[w][0][0];
  short* P1 = &sP[w][1][0];
  const int pwo = l15 * 72 + lg * 4;   // packed write base (+t4*16)
  const int pro = l15 * 72 + lg * 8;   // A-frag read base (+kk*32)

  const f32x4 fz = {0.f, 0.f, 0.f, 0.f};
  f32x4 Oacc[2][2];
  Oacc[0][0] = fz; Oacc[0][1] = fz; Oacc[1][0] = fz; Oacc[1][1] = fz;
  float den[2] = {0.f, 0.f};

  const int kt0 = z * 32, kt1 = kt0 + 32;
  const int kstart = kt0 * 64;

  const int kr = t >> 2, kc0 = (t & 3) * 8;
  const int vd = t >> 3, vk0 = (t & 7) * 8;
  const short* kg = Kb + (size_t)(kstart + kr) * 32 + kc0;
  const short* vg = Vb + (size_t)vd * 4096 + kstart + vk0;

  bf16x8 krg = *(const bf16x8*)kg;
  bf16x8 vrg = *(const bf16x8*)vg;
  *(bf16x8*)(&sK[0][0] + kr * 40 + kc0) = krg;
  *(bf16x8*)(&sV[0][0] + vd * 72 + vk0) = vrg;
  kg += 64 * 32; vg += 64;
  krg = *(const bf16x8*)kg;
  vrg = *(const bf16x8*)vg;
  __syncthreads();

  int kv = kstart / sl;
  int rem = (kv + 1) * sl - kstart;
  int cur = 0;

  bf16x8 vprev[2][2];   // V-frags of tile kt-1 (valid from 2nd iteration)
#pragma unroll
  for (int kk = 0; kk < 2; ++kk)
#pragma unroll
    for (int nt = 0; nt < 2; ++nt) vprev[kk][nt] = bf16x8{0,0,0,0,0,0,0,0};

#pragma unroll 2
  for (int kt = kt0; kt < kt1; ++kt) {
    // park tile kt+1 (kt-1's LDS copy is dead: its V was consumed via vprev regs)
    *(bf16x8*)(&sK[cur ^ 1][0] + kr * 40 + kc0) = krg;
    *(bf16x8*)(&sV[cur ^ 1][0] + vd * 72 + vk0) = vrg;
    const int adv = (kt + 2 < kt1) ? 1 : 0;
    kg += adv * (64 * 32); vg += adv * 64;
    krg = *(const bf16x8*)kg;
    vrg = *(const bf16x8*)vg;

    const short* sKc = &sK[cur][0];
    const short* sVc = &sV[cur][0];

    // QK both g
    f32x4 S[2][4];
#pragma unroll
    for (int t4 = 0; t4 < 4; ++t4) {
      bf16x8 kf = *(const bf16x8*)(sKc + (t4 * 16 + l15) * 40 + lg * 8);
      S[0][t4] = __builtin_amdgcn_mfma_f32_16x16x32_bf16(kf, qf[0], fz, 0, 0, 0);
      S[1][t4] = __builtin_amdgcn_mfma_f32_16x16x32_bf16(kf, qf[1], fz, 0, 0, 0);
    }

    // deferred PV(g1, kt-1): P1 written last iter; V in registers
    if (kt > kt0) {
#pragma unroll
      for (int kk = 0; kk < 2; ++kk) {
        bf16x8 pf = *(const bf16x8*)(P1 + pro + kk * 32);
        Oacc[1][0] = __builtin_amdgcn_mfma_f32_16x16x32_bf16(pf, vprev[kk][0], Oacc[1][0], 0, 0, 0);
        Oacc[1][1] = __builtin_amdgcn_mfma_f32_16x16x32_bf16(pf, vprev[kk][1], Oacc[1][1], 0, 0, 0);
      }
    }

    const int kb0 = kt * 64;
    const bool uni = (rem >= 64);
    const float lb0 = (qv[0] == kv) ? lbs : lbd;
    const float lb1 = (qv[1] == kv) ? lbs : lbd;

    // exp(g0) -> P0  (trans pipe; overlaps the PV(g1) MFMAs above)
    if (uni) {
#pragma unroll
      for (int t4 = 0; t4 < 4; ++t4) {
        float p0 = EXP2(S[0][t4][0] + lb0);
        float p1 = EXP2(S[0][t4][1] + lb0);
        float p2 = EXP2(S[0][t4][2] + lb0);
        float p3 = EXP2(S[0][t4][3] + lb0);
        den[0] += (p0 + p1) + (p2 + p3);
        u32x2 u; u.x = cvt_pk_bf16(p0, p1); u.y = cvt_pk_bf16(p2, p3);
        *(u32x2*)(P0 + pwo + t4 * 16) = u;
      }
    } else {
#pragma unroll
      for (int t4 = 0; t4 < 4; ++t4) {
        const int gk = kb0 + t4 * 16 + lg * 4;
        float p[4];
#pragma unroll
        for (int j = 0; j < 4; ++j) {
          float lbj = ((unsigned)(gk + j - qlo[0]) < (unsigned)sl) ? lbs : lbd;
          p[j] = EXP2(S[0][t4][j] + lbj);
          den[0] += p[j];
        }
        u32x2 u; u.x = cvt_pk_bf16(p[0], p[1]); u.y = cvt_pk_bf16(p[2], p[3]);
        *(u32x2*)(P0 + pwo + t4 * 16) = u;
      }
    }

    // V-frags for tile kt (used by PV(g0) now and PV(g1) next iteration)
    bf16x8 vcur[2][2];
#pragma unroll
    for (int kk = 0; kk < 2; ++kk)
#pragma unroll
      for (int nt = 0; nt < 2; ++nt)
        vcur[kk][nt] = *(const bf16x8*)(sVc + (nt * 16 + l15) * 72 + kk * 32 + lg * 8);

    // exp(g1) -> P1  (fills the P0 write->read gap)
    if (uni) {
#pragma unroll
      for (int t4 = 0; t4 < 4; ++t4) {
        float p0 = EXP2(S[1][t4][0] + lb1);
        float p1 = EXP2(S[1][t4][1] + lb1);
        float p2 = EXP2(S[1][t4][2] + lb1);
        float p3 = EXP2(S[1][t4][3] + lb1);
        den[1] += (p0 + p1) + (p2 + p3);
        u32x2 u; u.x = cvt_pk_bf16(p0, p1); u.y = cvt_pk_bf16(p2, p3);
        *(u32x2*)(P1 + pwo + t4 * 16) = u;
      }
    } else {
#pragma unroll
      for (int t4 = 0; t4 < 4; ++t4) {
        const int gk = kb0 + t4 * 16 + lg * 4;
        float p[4];
#pragma unroll
        for (int j = 0; j < 4; ++j) {
          float lbj = ((unsigned)(gk + j - qlo[1]) < (unsigned)sl) ? lbs : lbd;
          p[j] = EXP2(S[1][t4][j] + lbj);
          den[1] += p[j];
        }
        u32x2 u; u.x = cvt_pk_bf16(p[0], p[1]); u.y = cvt_pk_bf16(p[2], p[3]);
        *(u32x2*)(P1 + pwo + t4 * 16) = u;
      }
    }

    // PV(g0, kt): P0 just written (same-wave lgkm), V from registers
#pragma unroll
    for (int kk = 0; kk < 2; ++kk) {
      bf16x8 pf = *(const bf16x8*)(P0 + pro + kk * 32);
      Oacc[0][0] = __builtin_amdgcn_mfma_f32_16x16x32_bf16(pf, vcur[kk][0], Oacc[0][0], 0, 0, 0);
      Oacc[0][1] = __builtin_amdgcn_mfma_f32_16x16x32_bf16(pf, vcur[kk][1], Oacc[0][1], 0, 0, 0);
    }

    rem -= 64;
    while (rem <= 0) { kv += 1; rem += sl; }

    __syncthreads();
    cur ^= 1;
#pragma unroll
    for (int kk = 0; kk < 2; ++kk)
#pragma unroll
      for (int nt = 0; nt < 2; ++nt) vprev[kk][nt] = vcur[kk][nt];
  }

  // epilogue: deferred PV(g1) of the final tile
#pragma unroll
  for (int kk = 0; kk < 2; ++kk) {
    bf16x8 pf = *(const bf16x8*)(P1 + pro + kk * 32);
    Oacc[1][0] = __builtin_amdgcn_mfma_f32_16x16x32_bf16(pf, vprev[kk][0], Oacc[1][0], 0, 0, 0);
    Oacc[1][1] = __builtin_amdgcn_mfma_f32_16x16x32_bf16(pf, vprev[kk][1], Oacc[1][1], 0, 0, 0);
  }

  // reduce den across lg groups (lanes with same l15)
#pragma unroll
  for (int g = 0; g < 2; ++g) {
    den[g] += __shfl_xor(den[g], 16, 64);
    den[g] += __shfl_xor(den[g], 32, 64);
  }

  const size_t zb = ((size_t)z * 16 + bh) * 4096;
  if (lg == 0) {
#pragma unroll
    for (int g = 0; g < 2; ++g)
      denp[zb + qb + g * 16 + l15] = den[g];
  }
#pragma unroll
  for (int g = 0; g < 2; ++g)
#pragma unroll
    for (int nt = 0; nt < 2; ++nt)
#pragma unroll
      for (int j = 0; j < 4; ++j) {
        const int n = qb + g * 16 + lg * 4 + j;
        Op[(zb + n) * 32 + nt * 16 + l15] = Oacc[g][nt][j];
      }
}

// ---------------------------------------------------------------------------
// Combine K-split partials: attno[b][n][h*32+d] = (O0+O1)/(d0+d1) as bf16.
// ---------------------------------------------------------------------------
__global__ __launch_bounds__(256) void combine(
    const float* __restrict__ Op, const float* __restrict__ denp,
    short* __restrict__ attno)
{
  const int id = blockIdx.x * 256 + threadIdx.x;   // 16*4096*8
  const int d4 = (id & 7) * 4;
  const int n  = (id >> 3) & 4095;
  const int bh = id >> 15;
  const size_t base = ((size_t)bh * 4096 + n) * 32 + d4;
  const size_t zoff = (size_t)16 * 4096 * 32;
  f32x4 o0 = *(const f32x4*)(Op + base);
  f32x4 o1 = *(const f32x4*)(Op + zoff + base);
  const float rd = 1.0f / (denp[bh * 4096 + n] + denp[16 * 4096 + bh * 4096 + n]);
  const int b = bh >> 3, hh = bh & 7;
  u32x2 u;
  u.x = cvt_pk_bf16((o0[0] + o1[0]) * rd, (o0[1] + o1[1]) * rd);
  u.y = cvt_pk_bf16((o0[2] + o1[2]) * rd, (o0[3] + o1[3]) * rd);
  *(u32x2*)(attno + ((size_t)(b * 4096 + n) * 256 + hh * 32 + d4)) = u;
}

// ---------------------------------------------------------------------------
// o-proj GEMM (proven, verbatim; A_BF16=1, OUT_BF16=0)
// ---------------------------------------------------------------------------
template<int A_BF16, int OUT_BF16>
__global__ __launch_bounds__(256) void gemm_mfma(
    const void* __restrict__ Ain,
    const float* __restrict__ W0, const float* __restrict__ W1, const float* __restrict__ W2,
    const float* __restrict__ b0, const float* __restrict__ b1, const float* __restrict__ b2,
    void* __restrict__ Cout, int Ntot)
{
  __shared__ short sA[128 * 40];
  __shared__ short sB[64 * 40];
  const int t = threadIdx.x;
  const int w = t >> 6, l = t & 63;
  const int l15 = l & 15, lg = l >> 4;
  const int rbase = blockIdx.x * 128;
  const int cgbase = blockIdx.y * 64;
  const int mat = cgbase >> 8;
  const float* W = (mat == 0) ? W0 : ((mat == 1) ? W1 : W2);
  const float* bias = (mat == 0) ? b0 : ((mat == 1) ? b1 : b2);
  const int wbase = cgbase & 255;

  const int ar = t >> 1, akc = (t & 1) * 16;
  const int br = t >> 2, bkc = (t & 3) * 8;

  const float* Bg = W + (size_t)(wbase + br) * 256 + bkc;
  const float* Agf = (const float*)Ain + (size_t)(rbase + ar) * 256 + akc;
  const short* Agh = (const short*)Ain + (size_t)(rbase + ar) * 256 + akc;

  const int wr = w >> 1, wc = w & 1;

  f32x4 acc[4][2];
#pragma unroll
  for (int i = 0; i < 4; ++i) {
    acc[i][0] = {0.f, 0.f, 0.f, 0.f};
    acc[i][1] = {0.f, 0.f, 0.f, 0.f};
  }

  for (int k0 = 0; k0 < 256; k0 += 32) {
    u32x4 pa0, pa1;
    if constexpr (A_BF16) {
      pa0 = *(const u32x4*)(Agh + k0);
      pa1 = *(const u32x4*)(Agh + k0 + 8);
    } else {
      f32x4 a0 = *(const f32x4*)(Agf + k0);
      f32x4 a1 = *(const f32x4*)(Agf + k0 + 4);
      f32x4 a2 = *(const f32x4*)(Agf + k0 + 8);
      f32x4 a3 = *(const f32x4*)(Agf + k0 + 12);
      pa0.x = cvt_pk_bf16(a0[0], a0[1]); pa0.y = cvt_pk_bf16(a0[2], a0[3]);
      pa0.z = cvt_pk_bf16(a1[0], a1[1]); pa0.w = cvt_pk_bf16(a1[2], a1[3]);
      pa1.x = cvt_pk_bf16(a2[0], a2[1]); pa1.y = cvt_pk_bf16(a2[2], a2[3]);
      pa1.z = cvt_pk_bf16(a3[0], a3[1]); pa1.w = cvt_pk_bf16(a3[2], a3[3]);
    }
    f32x4 bv0 = *(const f32x4*)(Bg + k0);
    f32x4 bv1 = *(const f32x4*)(Bg + k0 + 4);
    u32x4 pb;
    pb.x = cvt_pk_bf16(bv0[0], bv0[1]); pb.y = cvt_pk_bf16(bv0[2], bv0[3]);
    pb.z = cvt_pk_bf16(bv1[0], bv1[1]); pb.w = cvt_pk_bf16(bv1[2], bv1[3]);

    __syncthreads();
    *(u32x4*)(sA + ar * 40 + akc)     = pa0;
    *(u32x4*)(sA + ar * 40 + akc + 8) = pa1;
    *(u32x4*)(sB + br * 40 + bkc)     = pb;
    __syncthreads();

    bf16x8 af[4], bfr[2];
#pragma unroll
    for (int i = 0; i < 4; ++i)
      af[i] = *(const bf16x8*)(sA + (wr * 64 + i * 16 + l15) * 40 + lg * 8);
#pragma unroll
    for (int j = 0; j < 2; ++j)
      bfr[j] = *(const bf16x8*)(sB + (wc * 32 + j * 16 + l15) * 40 + lg * 8);
#pragma unroll
    for (int i = 0; i < 4; ++i)
#pragma unroll
      for (int j = 0; j < 2; ++j)
        acc[i][j] = __builtin_amdgcn_mfma_f32_16x16x32_bf16(af[i], bfr[j], acc[i][j], 0, 0, 0);
  }

#pragma unroll
  for (int i = 0; i < 4; ++i)
#pragma unroll
    for (int j = 0; j < 2; ++j) {
      const int n = cgbase + wc * 32 + j * 16 + l15;
      const float bv = bias[wbase + wc * 32 + j * 16 + l15];
#pragma unroll
      for (int jj = 0; jj < 4; ++jj) {
        const size_t m = (size_t)(rbase + wr * 64 + i * 16 + lg * 4 + jj);
        const float val = acc[i][j][jj] + bv;
        if constexpr (OUT_BF16) ((short*)Cout)[m * Ntot + n] = f2bf(val);
        else                    ((float*)Cout)[m * Ntot + n] = val;
      }
    }
}

// ---------------------------------------------------------------------------
extern "C" void kernel_launch(void* const* d_in, const int* in_sizes, int n_in,
                              void* d_out, int out_size, void* d_ws, size_t ws_size,
                              hipStream_t stream) {
  (void)in_sizes; (void)n_in; (void)out_size; (void)ws_size;
  const float* hs = (const float*)d_in[0];
  const float* qw = (const float*)d_in[1];
  const float* qb = (const float*)d_in[2];
  const float* kw = (const float*)d_in[3];
  const float* kb = (const float*)d_in[4];
  const float* vw = (const float*)d_in[5];
  const float* vb = (const float*)d_in[6];
  const float* ow = (const float*)d_in[7];
  const float* ob = (const float*)d_in[8];
  const float* ab = (const float*)d_in[9];
  const int* sl   = (const int*)d_in[11];
  float* out = (float*)d_out;

  char* ws = (char*)d_ws;
  float* Op   = (float*)(ws);                    // 2*16*4096*32*4 = 16,777,216
  short* Qbf  = (short*)(ws + 16777216);         // 4,194,304
  short* Kbf  = (short*)(ws + 20971520);         // 4,194,304
  short* Vtb  = (short*)(ws + 25165824);         // 4,194,304 (transposed)
  float* denp = (float*)(ws + 29360128);         // 524,288
  short* attno= (short*)(ws + 29884416);         // 4,194,304

  // QKV projection + fused rope/scale(incl. log2e)/pack/V-transpose
  gemm_qkv_rope<<<dim3(64, 12), 256, 0, stream>>>(hs, qw, kw, vw, qb, kb, vb, Qbf, Kbf, Vtb);
  // attention (g-pipelined PV, 128 q-rows/block), K-split in 2
  attn_fwd<<<dim3(32, 16, 2), 256, 0, stream>>>(Qbf, Kbf, Vtb, ab, sl, Op, denp);
  // merge partials -> bf16 attention output
  combine<<<dim3(2048), 256, 0, stream>>>(Op, denp, attno);
  // output projection
  gemm_mfma<1, 0><<<dim3(64, 4), 256, 0, stream>>>(attno, ow, ow, ow, ob, ob, ob, out, 256);
}